// Round 9
// baseline (231.606 us; speedup 1.0000x reference)
//
#include <hip/hip_runtime.h>
#include <math.h>

#define B_    4
#define NS    2048
#define EMB_  1024
#define NH    16
#define HD    64
#define MR    (B_*NS)        // 8192 rows

typedef __attribute__((ext_vector_type(8))) short bf16x8;
typedef __attribute__((ext_vector_type(4))) float f32x4;

#define AS1 __attribute__((address_space(1)))
#define AS3 __attribute__((address_space(3)))

#if __has_builtin(__builtin_amdgcn_exp2f)
#define EXP2F(x) __builtin_amdgcn_exp2f(x)
#else
#define EXP2F(x) exp2f(x)
#endif

__device__ __forceinline__ unsigned short f2bf(float f) {
  unsigned int x = __float_as_uint(f);
  x += 0x7fffu + ((x >> 16) & 1u);   // round-to-nearest-even
  return (unsigned short)(x >> 16);
}

__device__ __forceinline__ unsigned int cvt_pk_bf16(float lo, float hi) {
  unsigned int r;
  asm("v_cvt_pk_bf16_f32 %0, %1, %2" : "=v"(r) : "v"(lo), "v"(hi));
  return r;
}

// ---------------------------------------------------------------------------
// fp32 -> bf16 conversion for x, w_qkv, w_proj (grid-stride, float4 in)
// ---------------------------------------------------------------------------
__global__ __launch_bounds__(256) void cvt_kernel(
    const float* __restrict__ x,  unsigned short* __restrict__ xb,  int nx,
    const float* __restrict__ w1, unsigned short* __restrict__ w1b, int n1,
    const float* __restrict__ w2, unsigned short* __restrict__ w2b, int n2) {
  const int total = (nx + n1 + n2) >> 2;
  for (int i = blockIdx.x * blockDim.x + threadIdx.x; i < total;
       i += gridDim.x * blockDim.x) {
    const int idx = i << 2;
    const float* src;
    unsigned short* dst;
    if (idx < nx)            { src = x  + idx;            dst = xb  + idx; }
    else if (idx < nx + n1)  { src = w1 + (idx - nx);     dst = w1b + (idx - nx); }
    else                     { src = w2 + (idx - nx - n1); dst = w2b + (idx - nx - n1); }
    float4 v = *reinterpret_cast<const float4*>(src);
    uint2 p;
    p.x = (unsigned)f2bf(v.x) | ((unsigned)f2bf(v.y) << 16);
    p.y = (unsigned)f2bf(v.z) | ((unsigned)f2bf(v.w) << 16);
    *reinterpret_cast<uint2*>(dst) = p;
  }
}

// ---------------------------------------------------------------------------
// Shared MFMA GEMM main loop: C[128x128] tile, BK=64, 4 waves.
// ---------------------------------------------------------------------------
__device__ __forceinline__ void mfma_mainloop(
    const unsigned short* __restrict__ xg,
    const unsigned short* __restrict__ wg,
    unsigned short* Xs, unsigned short* Ws, f32x4 acc[4][4]) {
  const int tid = threadIdx.x;
  const int w = tid >> 6, l = tid & 63;
  const int lr = l & 15, lq = l >> 4;
  const int wm = w >> 1, wn = w & 1;
  const int rr = l >> 3;
  const int sl = (l & 7) ^ rr;

  for (int kt = 0; kt < 16; ++kt) {
    const int k0 = kt * 64;
#pragma unroll
    for (int i = 0; i < 4; ++i) {
      const int r0 = w * 32 + i * 8;
      __builtin_amdgcn_global_load_lds(
          (const AS1 unsigned int*)(const void*)(xg + (size_t)(r0 + rr) * 1024 + k0 + sl * 8),
          (AS3 unsigned int*)(void*)(Xs + r0 * 64), 16, 0, 0);
      __builtin_amdgcn_global_load_lds(
          (const AS1 unsigned int*)(const void*)(wg + (size_t)(r0 + rr) * 1024 + k0 + sl * 8),
          (AS3 unsigned int*)(void*)(Ws + r0 * 64), 16, 0, 0);
    }
    __syncthreads();

#pragma unroll
    for (int ks = 0; ks < 2; ++ks) {
      bf16x8 xf[4], wf[4];
#pragma unroll
      for (int i = 0; i < 4; ++i) {
        const int row = wm * 64 + i * 16 + lr;
        const int s2 = (ks * 4 + lq) ^ (row & 7);
        xf[i] = *reinterpret_cast<const bf16x8*>((const char*)Xs + row * 128 + s2 * 16);
      }
#pragma unroll
      for (int j = 0; j < 4; ++j) {
        const int row = wn * 64 + j * 16 + lr;
        const int s2 = (ks * 4 + lq) ^ (row & 7);
        wf[j] = *reinterpret_cast<const bf16x8*>((const char*)Ws + row * 128 + s2 * 16);
      }
#pragma unroll
      for (int i = 0; i < 4; ++i)
#pragma unroll
        for (int j = 0; j < 4; ++j)
          acc[i][j] = __builtin_amdgcn_mfma_f32_16x16x32_bf16(wf[j], xf[i], acc[i][j], 0, 0, 0);
    }
    __syncthreads();
  }
}

// ---------------------------------------------------------------------------
// GEMM1: qkv = x @ w_qkv^T + b_qkv -> bf16 q/k [B][H][NS][HD] and
// V^T DIRECTLY as vt [B][H][HD][NS] (vtrans fused away).
// q scaled by 0.125*log2(e)  (attention softmax runs in exp2 domain)
// ---------------------------------------------------------------------------
__global__ __launch_bounds__(256) void qkv_mfma_kernel(
    const unsigned short* __restrict__ xb, const unsigned short* __restrict__ wqb,
    const float* __restrict__ bias,
    unsigned short* __restrict__ qb, unsigned short* __restrict__ kb,
    unsigned short* __restrict__ vtb) {
  __shared__ __align__(16) unsigned short Xs[128 * 64];
  __shared__ __align__(16) unsigned short Ws[128 * 64];
  f32x4 acc[4][4];
  const f32x4 fz = {0.f, 0.f, 0.f, 0.f};
#pragma unroll
  for (int i = 0; i < 4; ++i)
#pragma unroll
    for (int j = 0; j < 4; ++j) acc[i][j] = fz;

  const int bm = blockIdx.x * 128, bn = blockIdx.y * 128;
  mfma_mainloop(xb + (size_t)bm * 1024, wqb + (size_t)bn * 1024, Xs, Ws, acc);

  const int tid = threadIdx.x;
  const int w = tid >> 6, l = tid & 63;
  const int lr = l & 15, lq = l >> 4;
  const int wm = w >> 1, wn = w & 1;
#pragma unroll
  for (int i = 0; i < 4; ++i) {
    const int mrow = bm + wm * 64 + i * 16 + lr;
    const int b = mrow >> 11;
    const int nseq = mrow & (NS - 1);
#pragma unroll
    for (int j = 0; j < 4; ++j) {
      const int col0 = bn + wn * 64 + j * 16 + lq * 4;
      const int which = col0 >> 10;
      const int e = col0 & 1023;
      const int hh = e >> 6, d0 = e & 63;
      const float v0 = acc[i][j][0] + bias[col0 + 0];
      const float v1 = acc[i][j][1] + bias[col0 + 1];
      const float v2 = acc[i][j][2] + bias[col0 + 2];
      const float v3 = acc[i][j][3] + bias[col0 + 3];
      if (which < 2) {
        unsigned short* dst = (which == 0) ? qb : kb;
        const float sc = (which == 0) ? 0.18033688f : 1.0f;  // 0.125*log2e
        uint2 pk;
        pk.x = (unsigned)f2bf(v0 * sc) | ((unsigned)f2bf(v1 * sc) << 16);
        pk.y = (unsigned)f2bf(v2 * sc) | ((unsigned)f2bf(v3 * sc) << 16);
        *reinterpret_cast<uint2*>(&dst[(((size_t)b * NH + hh) * NS + nseq) * HD + d0]) = pk;
      } else {
        // V^T: vt[b][h][d][n], d = d0..d0+3 (within one head: d0 <= 60)
        unsigned short* dt =
            vtb + (((size_t)b * NH + hh) * HD + d0) * NS + nseq;
        dt[0 * NS] = f2bf(v0);
        dt[1 * NS] = f2bf(v1);
        dt[2 * NS] = f2bf(v2);
        dt[3 * NS] = f2bf(v3);
      }
    }
  }
}

// ---------------------------------------------------------------------------
// GEMM2: out = att(bf16) @ w_proj^T + b_proj -> fp32
// ---------------------------------------------------------------------------
__global__ __launch_bounds__(256) void proj_mfma_kernel(
    const unsigned short* __restrict__ attb, const unsigned short* __restrict__ wpb,
    const float* __restrict__ bias, float* __restrict__ out) {
  __shared__ __align__(16) unsigned short Xs[128 * 64];
  __shared__ __align__(16) unsigned short Ws[128 * 64];
  f32x4 acc[4][4];
  const f32x4 fz = {0.f, 0.f, 0.f, 0.f};
#pragma unroll
  for (int i = 0; i < 4; ++i)
#pragma unroll
    for (int j = 0; j < 4; ++j) acc[i][j] = fz;

  const int bm = blockIdx.x * 128, bn = blockIdx.y * 128;
  mfma_mainloop(attb + (size_t)bm * 1024, wpb + (size_t)bn * 1024, Xs, Ws, acc);

  const int tid = threadIdx.x;
  const int w = tid >> 6, l = tid & 63;
  const int lr = l & 15, lq = l >> 4;
  const int wm = w >> 1, wn = w & 1;
#pragma unroll
  for (int i = 0; i < 4; ++i) {
    const int mrow = bm + wm * 64 + i * 16 + lr;
#pragma unroll
    for (int j = 0; j < 4; ++j) {
      const int col0 = bn + wn * 64 + j * 16 + lq * 4;
      const float4 b4 = *reinterpret_cast<const float4*>(&bias[col0]);
      float4 v;
      v.x = acc[i][j][0] + b4.x; v.y = acc[i][j][1] + b4.y;
      v.z = acc[i][j][2] + b4.z; v.w = acc[i][j][3] + b4.w;
      *reinterpret_cast<float4*>(&out[(size_t)mrow * EMB_ + col0]) = v;
    }
  }
}

// ---------------------------------------------------------------------------
// Flash attention v6: R4 structure verbatim; ONLY change = seeded-accumulator
// defer-max. QK^T accumulator is initialized with -m_ (legal: S-layout puts
// one q-row per lane, q=lr, so all 4 C-regs share this lane's m_), so the
// common-path P = exp2(s') needs NO per-element subtract. Tile 0 is FORCED
// onto the rescale path so m_ becomes the true running max (identical
// operating regime to R4: P bounded, m_ tracks max). Rescale tiles keep the
// subtract in a wave-uniform branch.
// Block = (b,h,64 q-rows), 4 waves x 16 q-rows, KV tiles of 64.
// ---------------------------------------------------------------------------
__global__ __launch_bounds__(256) void attn_mfma6_kernel(
    const unsigned short* __restrict__ qb, const unsigned short* __restrict__ kb,
    const unsigned short* __restrict__ vt, unsigned short* __restrict__ attb) {
  __shared__ __align__(16) unsigned short Ks[2][64 * 64];   // [kv][d] swizzled
  __shared__ __align__(16) unsigned short VT[2][64 * 64];   // [d][kv] swizzled
  __shared__ __align__(16) unsigned short Ps[4][16 * 64];   // per-wave P [q][kv] swizzled

  // bijective XCD swizzle: 8 XCDs x 256 blocks; each XCD gets 8 whole heads
  const int wg = blockIdx.x;                 // 0..2047
  const int swz = (wg & 7) * 256 + (wg >> 3);
  const int qblk = swz & 31;
  const int head = swz >> 5;                 // 0..63
  const int h = head & 15;
  const int bq = head >> 4;
  const int q0 = qblk * 64;

  const int tid = threadIdx.x;
  const int w = tid >> 6, l = tid & 63;
  const int lr = l & 15, lq = l >> 4;
  const size_t headoff = ((size_t)bq * NH + h) * (size_t)NS * HD;
  const unsigned short* qp = qb + headoff;
  const unsigned short* kp = kb + headoff;
  const unsigned short* vtp = vt + headoff;   // [HD][NS]

  // Q fragments (scale 0.125*log2e folded): B[row=lr][k=lq*8..]
  bf16x8 qf[2];
  {
    const unsigned short* qrow = qp + (size_t)(q0 + w * 16 + lr) * HD + lq * 8;
    qf[0] = *reinterpret_cast<const bf16x8*>(qrow);
    qf[1] = *reinterpret_cast<const bf16x8*>(qrow + 32);
  }

  const f32x4 fz = {0.f, 0.f, 0.f, 0.f};
  float m_ = 0.f, l_ = 0.f;
  f32x4 o_[4];
#pragma unroll
  for (int d = 0; d < 4; ++d) o_[d] = fz;

  const int srow = l >> 3, sslot = l & 7;

  // ---- prologue: stage tile 0 into buf 0 ----
#pragma unroll
  for (int n = 0; n < 2; ++n) {
    const int r0 = (n * 4 + w) * 8;
    const int row = r0 + srow;
    const int so = (sslot ^ (row & 7)) * 8;
    __builtin_amdgcn_global_load_lds(
        (const AS1 unsigned int*)(const void*)(kp + row * 64 + so),
        (AS3 unsigned int*)(void*)(&Ks[0][0] + r0 * 64), 16, 0, 0);
    __builtin_amdgcn_global_load_lds(
        (const AS1 unsigned int*)(const void*)(vtp + (size_t)row * NS + so),
        (AS3 unsigned int*)(void*)(&VT[0][0] + r0 * 64), 16, 0, 0);
  }
  __syncthreads();

  int buf = 0;
  for (int kt = 0; kt < NS / 64; ++kt) {
    // ---- issue next-tile stage into buf^1 (drained at this iter's barrier) ----
    if (kt < NS / 64 - 1) {
      const unsigned short* knext = kp + (size_t)(kt + 1) * 64 * 64;
      const int vcol = (kt + 1) * 64;
#pragma unroll
      for (int n = 0; n < 2; ++n) {
        const int r0 = (n * 4 + w) * 8;
        const int row = r0 + srow;
        const int so = (sslot ^ (row & 7)) * 8;
        __builtin_amdgcn_global_load_lds(
            (const AS1 unsigned int*)(const void*)(knext + row * 64 + so),
            (AS3 unsigned int*)(void*)(&Ks[buf ^ 1][0] + r0 * 64), 16, 0, 0);
        __builtin_amdgcn_global_load_lds(
            (const AS1 unsigned int*)(const void*)(vtp + (size_t)row * NS + vcol + so),
            (AS3 unsigned int*)(void*)(&VT[buf ^ 1][0] + r0 * 64), 16, 0, 0);
      }
    }

    // ---- S' = K Q^T - m_ (seeded): lane holds S'[q=lr][kv=j4*16+lq*4+r] ----
    const f32x4 seed = {-m_, -m_, -m_, -m_};
    f32x4 s_[4];
#pragma unroll
    for (int j4 = 0; j4 < 4; ++j4) s_[j4] = seed;
#pragma unroll
    for (int ks = 0; ks < 2; ++ks) {
#pragma unroll
      for (int j4 = 0; j4 < 4; ++j4) {
        const int row = j4 * 16 + lr;
        const int s2 = (ks * 4 + lq) ^ (row & 7);
        bf16x8 kf = *reinterpret_cast<const bf16x8*>((const char*)&Ks[buf][0] + row * 128 + s2 * 16);
        s_[j4] = __builtin_amdgcn_mfma_f32_16x16x32_bf16(kf, qf[ks], s_[j4], 0, 0, 0);
      }
    }

    // ---- online softmax in exp2 domain; s_ is already shifted by -m_ ----
    float tm = fmaxf(fmaxf(fmaxf(s_[0][0], s_[0][1]), fmaxf(s_[0][2], s_[0][3])),
                     fmaxf(fmaxf(s_[1][0], s_[1][1]), fmaxf(s_[1][2], s_[1][3])));
    tm = fmaxf(tm, fmaxf(fmaxf(fmaxf(s_[2][0], s_[2][1]), fmaxf(s_[2][2], s_[2][3])),
                         fmaxf(fmaxf(s_[3][0], s_[3][1]), fmaxf(s_[3][2], s_[3][3]))));
    tm = fmaxf(tm, __shfl_xor(tm, 16, 64));
    tm = fmaxf(tm, __shfl_xor(tm, 32, 64));
    float rs = 0.f;
    const bool force = (kt == 0);
    if (force || !__all(tm <= 11.5416f)) {
      // rescale path (tile 0 forced so m_ becomes the true running max)
      const float ts = force ? tm : fmaxf(tm, 0.f);
      const float fac = EXP2F(-ts);
      m_ += ts;
      l_ *= fac;
#pragma unroll
      for (int r = 0; r < 4; ++r) {
        const float fr = __shfl(fac, (l & 48) | (lq * 4 + r), 64);
        o_[0][r] *= fr; o_[1][r] *= fr; o_[2][r] *= fr; o_[3][r] *= fr;
      }
#pragma unroll
      for (int j4 = 0; j4 < 4; ++j4) {
        const float p0 = EXP2F(s_[j4][0] - ts);
        const float p1 = EXP2F(s_[j4][1] - ts);
        const float p2 = EXP2F(s_[j4][2] - ts);
        const float p3 = EXP2F(s_[j4][3] - ts);
        rs += (p0 + p1) + (p2 + p3);
        const int s16 = (j4 * 2 + (lq >> 1)) ^ (lr & 7);
        uint2 pk;
        pk.x = cvt_pk_bf16(p0, p1);
        pk.y = cvt_pk_bf16(p2, p3);
        *reinterpret_cast<uint2*>((char*)&Ps[w][0] + lr * 128 + s16 * 16 + (lq & 1) * 8) = pk;
      }
    } else {
      // fast path: no subtract at all (seed already applied -m_)
#pragma unroll
      for (int j4 = 0; j4 < 4; ++j4) {
        const float p0 = EXP2F(s_[j4][0]);
        const float p1 = EXP2F(s_[j4][1]);
        const float p2 = EXP2F(s_[j4][2]);
        const float p3 = EXP2F(s_[j4][3]);
        rs += (p0 + p1) + (p2 + p3);
        const int s16 = (j4 * 2 + (lq >> 1)) ^ (lr & 7);
        uint2 pk;
        pk.x = cvt_pk_bf16(p0, p1);
        pk.y = cvt_pk_bf16(p2, p3);
        *reinterpret_cast<uint2*>((char*)&Ps[w][0] + lr * 128 + s16 * 16 + (lq & 1) * 8) = pk;
      }
    }
    rs += __shfl_xor(rs, 16, 64);
    rs += __shfl_xor(rs, 32, 64);
    l_ += rs;

    // ---- O += P V ----
#pragma unroll
    for (int ks = 0; ks < 2; ++ks) {
      const int sp = (ks * 4 + lq) ^ (lr & 7);
      bf16x8 pf = *reinterpret_cast<const bf16x8*>((const char*)&Ps[w][0] + lr * 128 + sp * 16);
#pragma unroll
      for (int d = 0; d < 4; ++d) {
        const int rowv = d * 16 + lr;
        const int s2 = (ks * 4 + lq) ^ (rowv & 7);
        bf16x8 vf = *reinterpret_cast<const bf16x8*>((const char*)&VT[buf][0] + rowv * 128 + s2 * 16);
        o_[d] = __builtin_amdgcn_mfma_f32_16x16x32_bf16(pf, vf, o_[d], 0, 0, 0);
      }
    }
    __syncthreads();   // drains vmcnt (next tile staged) + frees buf for overwrite
    buf ^= 1;
  }

  // ---- epilogue: attb[b][n][h*64+d] (bf16) ----
#pragma unroll
  for (int r = 0; r < 4; ++r) {
    const float lsum = __shfl(l_, (l & 48) | (lq * 4 + r), 64);
    const float inv = 1.0f / lsum;
    const size_t row = (size_t)bq * NS + q0 + w * 16 + lq * 4 + r;
#pragma unroll
    for (int d = 0; d < 4; ++d) {
      attb[row * EMB_ + h * HD + d * 16 + lr] = f2bf(o_[d][r] * inv);
    }
  }
}

// ---------------------------------------------------------------------------
extern "C" void kernel_launch(void* const* d_in, const int* in_sizes, int n_in,
                              void* d_out, int out_size, void* d_ws, size_t ws_size,
                              hipStream_t stream) {
  const float* x      = (const float*)d_in[0];
  const float* w_qkv  = (const float*)d_in[1];
  const float* b_qkv  = (const float*)d_in[2];
  const float* w_proj = (const float*)d_in[3];
  const float* b_proj = (const float*)d_in[4];
  float* out = (float*)d_out;

  const size_t per = (size_t)B_ * NH * NS * HD;        // 8,388,608
  unsigned short* qb   = (unsigned short*)d_ws;
  unsigned short* kb   = qb + per;
  unsigned short* vtb  = kb + per;                     // V^T [B][H][HD][NS]
  unsigned short* attb = vtb + per;                    // [B][NS][EMB] bf16
  unsigned short* xb   = attb + (size_t)MR * EMB_;     // x bf16
  unsigned short* wqb  = xb + (size_t)MR * EMB_;
  unsigned short* wpb  = wqb + (size_t)3 * EMB_ * EMB_;

  const int nx = MR * EMB_;
  const int n1 = 3 * EMB_ * EMB_;
  const int n2 = EMB_ * EMB_;
  cvt_kernel<<<2048, 256, 0, stream>>>(x, xb, nx, w_qkv, wqb, n1, w_proj, wpb, n2);

  dim3 g1(MR / 128, 3 * EMB_ / 128);     // 64 x 24
  qkv_mfma_kernel<<<g1, 256, 0, stream>>>(xb, wqb, b_qkv, qb, kb, vtb);

  attn_mfma6_kernel<<<2048, 256, 0, stream>>>(qb, kb, vtb, attb);

  dim3 g3(MR / 128, EMB_ / 128);         // 64 x 8
  proj_mfma_kernel<<<g3, 256, 0, stream>>>(attb, wpb, b_proj, out);
}

// Round 10
// 225.325 us; speedup vs baseline: 1.0279x; 1.0279x over previous
//
#include <hip/hip_runtime.h>
#include <math.h>

#define B_    4
#define NS    2048
#define EMB_  1024
#define NH    16
#define HD    64
#define MR    (B_*NS)        // 8192 rows

typedef __attribute__((ext_vector_type(8))) short bf16x8;
typedef __attribute__((ext_vector_type(4))) float f32x4;

#define AS1 __attribute__((address_space(1)))
#define AS3 __attribute__((address_space(3)))

#if __has_builtin(__builtin_amdgcn_exp2f)
#define EXP2F(x) __builtin_amdgcn_exp2f(x)
#else
#define EXP2F(x) exp2f(x)
#endif

__device__ __forceinline__ unsigned short f2bf(float f) {
  unsigned int x = __float_as_uint(f);
  x += 0x7fffu + ((x >> 16) & 1u);   // round-to-nearest-even
  return (unsigned short)(x >> 16);
}

__device__ __forceinline__ unsigned int cvt_pk_bf16(float lo, float hi) {
  unsigned int r;
  asm("v_cvt_pk_bf16_f32 %0, %1, %2" : "=v"(r) : "v"(lo), "v"(hi));
  return r;
}

// ---------------------------------------------------------------------------
// fp32 -> bf16 conversion for x, w_qkv, w_proj (grid-stride, float4 in)
// ---------------------------------------------------------------------------
__global__ __launch_bounds__(256) void cvt_kernel(
    const float* __restrict__ x,  unsigned short* __restrict__ xb,  int nx,
    const float* __restrict__ w1, unsigned short* __restrict__ w1b, int n1,
    const float* __restrict__ w2, unsigned short* __restrict__ w2b, int n2) {
  const int total = (nx + n1 + n2) >> 2;
  for (int i = blockIdx.x * blockDim.x + threadIdx.x; i < total;
       i += gridDim.x * blockDim.x) {
    const int idx = i << 2;
    const float* src;
    unsigned short* dst;
    if (idx < nx)            { src = x  + idx;            dst = xb  + idx; }
    else if (idx < nx + n1)  { src = w1 + (idx - nx);     dst = w1b + (idx - nx); }
    else                     { src = w2 + (idx - nx - n1); dst = w2b + (idx - nx - n1); }
    float4 v = *reinterpret_cast<const float4*>(src);
    uint2 p;
    p.x = (unsigned)f2bf(v.x) | ((unsigned)f2bf(v.y) << 16);
    p.y = (unsigned)f2bf(v.z) | ((unsigned)f2bf(v.w) << 16);
    *reinterpret_cast<uint2*>(dst) = p;
  }
}

// ---------------------------------------------------------------------------
// Shared MFMA GEMM main loop: C[128x128] tile, BK=64, 4 waves.
// ---------------------------------------------------------------------------
__device__ __forceinline__ void mfma_mainloop(
    const unsigned short* __restrict__ xg,
    const unsigned short* __restrict__ wg,
    unsigned short* Xs, unsigned short* Ws, f32x4 acc[4][4]) {
  const int tid = threadIdx.x;
  const int w = tid >> 6, l = tid & 63;
  const int lr = l & 15, lq = l >> 4;
  const int wm = w >> 1, wn = w & 1;
  const int rr = l >> 3;
  const int sl = (l & 7) ^ rr;

  for (int kt = 0; kt < 16; ++kt) {
    const int k0 = kt * 64;
#pragma unroll
    for (int i = 0; i < 4; ++i) {
      const int r0 = w * 32 + i * 8;
      __builtin_amdgcn_global_load_lds(
          (const AS1 unsigned int*)(const void*)(xg + (size_t)(r0 + rr) * 1024 + k0 + sl * 8),
          (AS3 unsigned int*)(void*)(Xs + r0 * 64), 16, 0, 0);
      __builtin_amdgcn_global_load_lds(
          (const AS1 unsigned int*)(const void*)(wg + (size_t)(r0 + rr) * 1024 + k0 + sl * 8),
          (AS3 unsigned int*)(void*)(Ws + r0 * 64), 16, 0, 0);
    }
    __syncthreads();

#pragma unroll
    for (int ks = 0; ks < 2; ++ks) {
      bf16x8 xf[4], wf[4];
#pragma unroll
      for (int i = 0; i < 4; ++i) {
        const int row = wm * 64 + i * 16 + lr;
        const int s2 = (ks * 4 + lq) ^ (row & 7);
        xf[i] = *reinterpret_cast<const bf16x8*>((const char*)Xs + row * 128 + s2 * 16);
      }
#pragma unroll
      for (int j = 0; j < 4; ++j) {
        const int row = wn * 64 + j * 16 + lr;
        const int s2 = (ks * 4 + lq) ^ (row & 7);
        wf[j] = *reinterpret_cast<const bf16x8*>((const char*)Ws + row * 128 + s2 * 16);
      }
#pragma unroll
      for (int i = 0; i < 4; ++i)
#pragma unroll
        for (int j = 0; j < 4; ++j)
          acc[i][j] = __builtin_amdgcn_mfma_f32_16x16x32_bf16(wf[j], xf[i], acc[i][j], 0, 0, 0);
    }
    __syncthreads();
  }
}

// ---------------------------------------------------------------------------
// GEMM1: qkv = x @ w_qkv^T + b_qkv -> bf16 q/k [B][H][NS][HD] and
// V^T DIRECTLY as vt [B][H][HD][NS] (vtrans fused away).
// q scaled by 0.125*log2(e)  (attention softmax runs in exp2 domain)
// ---------------------------------------------------------------------------
__global__ __launch_bounds__(256) void qkv_mfma_kernel(
    const unsigned short* __restrict__ xb, const unsigned short* __restrict__ wqb,
    const float* __restrict__ bias,
    unsigned short* __restrict__ qb, unsigned short* __restrict__ kb,
    unsigned short* __restrict__ vtb) {
  __shared__ __align__(16) unsigned short Xs[128 * 64];
  __shared__ __align__(16) unsigned short Ws[128 * 64];
  f32x4 acc[4][4];
  const f32x4 fz = {0.f, 0.f, 0.f, 0.f};
#pragma unroll
  for (int i = 0; i < 4; ++i)
#pragma unroll
    for (int j = 0; j < 4; ++j) acc[i][j] = fz;

  const int bm = blockIdx.x * 128, bn = blockIdx.y * 128;
  mfma_mainloop(xb + (size_t)bm * 1024, wqb + (size_t)bn * 1024, Xs, Ws, acc);

  const int tid = threadIdx.x;
  const int w = tid >> 6, l = tid & 63;
  const int lr = l & 15, lq = l >> 4;
  const int wm = w >> 1, wn = w & 1;
#pragma unroll
  for (int i = 0; i < 4; ++i) {
    const int mrow = bm + wm * 64 + i * 16 + lr;
    const int b = mrow >> 11;
    const int nseq = mrow & (NS - 1);
#pragma unroll
    for (int j = 0; j < 4; ++j) {
      const int col0 = bn + wn * 64 + j * 16 + lq * 4;
      const int which = col0 >> 10;
      const int e = col0 & 1023;
      const int hh = e >> 6, d0 = e & 63;
      const float v0 = acc[i][j][0] + bias[col0 + 0];
      const float v1 = acc[i][j][1] + bias[col0 + 1];
      const float v2 = acc[i][j][2] + bias[col0 + 2];
      const float v3 = acc[i][j][3] + bias[col0 + 3];
      if (which < 2) {
        unsigned short* dst = (which == 0) ? qb : kb;
        const float sc = (which == 0) ? 0.18033688f : 1.0f;  // 0.125*log2e
        uint2 pk;
        pk.x = (unsigned)f2bf(v0 * sc) | ((unsigned)f2bf(v1 * sc) << 16);
        pk.y = (unsigned)f2bf(v2 * sc) | ((unsigned)f2bf(v3 * sc) << 16);
        *reinterpret_cast<uint2*>(&dst[(((size_t)b * NH + hh) * NS + nseq) * HD + d0]) = pk;
      } else {
        // V^T: vt[b][h][d][n], d = d0..d0+3 (within one head: d0 <= 60)
        unsigned short* dt =
            vtb + (((size_t)b * NH + hh) * HD + d0) * NS + nseq;
        dt[0 * NS] = f2bf(v0);
        dt[1 * NS] = f2bf(v1);
        dt[2 * NS] = f2bf(v2);
        dt[3 * NS] = f2bf(v3);
      }
    }
  }
}

// ---------------------------------------------------------------------------
// GEMM2: out = att(bf16) @ w_proj^T + b_proj -> fp32
// ---------------------------------------------------------------------------
__global__ __launch_bounds__(256) void proj_mfma_kernel(
    const unsigned short* __restrict__ attb, const unsigned short* __restrict__ wpb,
    const float* __restrict__ bias, float* __restrict__ out) {
  __shared__ __align__(16) unsigned short Xs[128 * 64];
  __shared__ __align__(16) unsigned short Ws[128 * 64];
  f32x4 acc[4][4];
  const f32x4 fz = {0.f, 0.f, 0.f, 0.f};
#pragma unroll
  for (int i = 0; i < 4; ++i)
#pragma unroll
    for (int j = 0; j < 4; ++j) acc[i][j] = fz;

  const int bm = blockIdx.x * 128, bn = blockIdx.y * 128;
  mfma_mainloop(attb + (size_t)bm * 1024, wpb + (size_t)bn * 1024, Xs, Ws, acc);

  const int tid = threadIdx.x;
  const int w = tid >> 6, l = tid & 63;
  const int lr = l & 15, lq = l >> 4;
  const int wm = w >> 1, wn = w & 1;
#pragma unroll
  for (int i = 0; i < 4; ++i) {
    const int mrow = bm + wm * 64 + i * 16 + lr;
#pragma unroll
    for (int j = 0; j < 4; ++j) {
      const int col0 = bn + wn * 64 + j * 16 + lq * 4;
      const float4 b4 = *reinterpret_cast<const float4*>(&bias[col0]);
      float4 v;
      v.x = acc[i][j][0] + b4.x; v.y = acc[i][j][1] + b4.y;
      v.z = acc[i][j][2] + b4.z; v.w = acc[i][j][3] + b4.w;
      *reinterpret_cast<float4*>(&out[(size_t)mrow * EMB_ + col0]) = v;
    }
  }
}

// ---------------------------------------------------------------------------
// Flash attention v7: R4/R8 inner code verbatim; QBLK=128 per block with the
// SAME 4 waves — each wave handles two 16-row q-subtiles (qs=0,1)
// sequentially against each staged K/V tile. Staging/barriers/swizzles
// byte-identical to R8; only per-q state is duplicated (compile-time qs).
// Grid = 1024 = 256 CU x 4 blocks/CU (exact residency, no tail); K/V
// staging and HBM fetch halved; barrier drain amortized over 2x compute.
// ---------------------------------------------------------------------------
__global__ __launch_bounds__(256) void attn_mfma7_kernel(
    const unsigned short* __restrict__ qb, const unsigned short* __restrict__ kb,
    const unsigned short* __restrict__ vt, unsigned short* __restrict__ attb) {
  __shared__ __align__(16) unsigned short Ks[2][64 * 64];   // [kv][d] swizzled
  __shared__ __align__(16) unsigned short VT[2][64 * 64];   // [d][kv] swizzled
  __shared__ __align__(16) unsigned short Ps[4][16 * 64];   // per-wave P (reused across qs)

  // bijective XCD swizzle: 1024 blocks; consecutive swz in an XCD share a head
  const int wg = blockIdx.x;                 // 0..1023
  const int swz = (wg & 7) * 128 + (wg >> 3);
  const int qblk = swz & 15;                 // 16 q-blocks of 128
  const int head = swz >> 4;                 // 0..63
  const int h = head & 15;
  const int bq = head >> 4;
  const int q0 = qblk * 128;

  const int tid = threadIdx.x;
  const int w = tid >> 6, l = tid & 63;
  const int lr = l & 15, lq = l >> 4;
  const size_t headoff = ((size_t)bq * NH + h) * (size_t)NS * HD;
  const unsigned short* qp = qb + headoff;
  const unsigned short* kp = kb + headoff;
  const unsigned short* vtp = vt + headoff;   // [HD][NS]

  // Q fragments (scale 0.125*log2e folded): B[row=lr][k=lq*8..], two subtiles
  bf16x8 qf[2][2];
#pragma unroll
  for (int qs = 0; qs < 2; ++qs) {
    const unsigned short* qrow =
        qp + (size_t)(q0 + qs * 64 + w * 16 + lr) * HD + lq * 8;
    qf[qs][0] = *reinterpret_cast<const bf16x8*>(qrow);
    qf[qs][1] = *reinterpret_cast<const bf16x8*>(qrow + 32);
  }

  const f32x4 fz = {0.f, 0.f, 0.f, 0.f};
  float m_[2] = {-1e30f, -1e30f}, l_[2] = {0.f, 0.f};
  f32x4 o_[2][4];
#pragma unroll
  for (int qs = 0; qs < 2; ++qs)
#pragma unroll
    for (int d = 0; d < 4; ++d) o_[qs][d] = fz;

  const int srow = l >> 3, sslot = l & 7;

  // ---- prologue: stage tile 0 into buf 0 (verbatim R8) ----
#pragma unroll
  for (int n = 0; n < 2; ++n) {
    const int r0 = (n * 4 + w) * 8;
    const int row = r0 + srow;
    const int so = (sslot ^ (row & 7)) * 8;
    __builtin_amdgcn_global_load_lds(
        (const AS1 unsigned int*)(const void*)(kp + row * 64 + so),
        (AS3 unsigned int*)(void*)(&Ks[0][0] + r0 * 64), 16, 0, 0);
    __builtin_amdgcn_global_load_lds(
        (const AS1 unsigned int*)(const void*)(vtp + (size_t)row * NS + so),
        (AS3 unsigned int*)(void*)(&VT[0][0] + r0 * 64), 16, 0, 0);
  }
  __syncthreads();

  int buf = 0;
  for (int kt = 0; kt < NS / 64; ++kt) {
    // ---- issue next-tile stage into buf^1 (verbatim R8) ----
    if (kt < NS / 64 - 1) {
      const unsigned short* knext = kp + (size_t)(kt + 1) * 64 * 64;
      const int vcol = (kt + 1) * 64;
#pragma unroll
      for (int n = 0; n < 2; ++n) {
        const int r0 = (n * 4 + w) * 8;
        const int row = r0 + srow;
        const int so = (sslot ^ (row & 7)) * 8;
        __builtin_amdgcn_global_load_lds(
            (const AS1 unsigned int*)(const void*)(knext + row * 64 + so),
            (AS3 unsigned int*)(void*)(&Ks[buf ^ 1][0] + r0 * 64), 16, 0, 0);
        __builtin_amdgcn_global_load_lds(
            (const AS1 unsigned int*)(const void*)(vtp + (size_t)row * NS + vcol + so),
            (AS3 unsigned int*)(void*)(&VT[buf ^ 1][0] + r0 * 64), 16, 0, 0);
      }
    }

#pragma unroll
    for (int qs = 0; qs < 2; ++qs) {
      // ---- S^T = K Q^T : lane holds P[q=lr][kv = j4*16 + lq*4 + r] ----
      f32x4 s_[4];
#pragma unroll
      for (int j4 = 0; j4 < 4; ++j4) s_[j4] = fz;
#pragma unroll
      for (int ks = 0; ks < 2; ++ks) {
#pragma unroll
        for (int j4 = 0; j4 < 4; ++j4) {
          const int row = j4 * 16 + lr;
          const int s2 = (ks * 4 + lq) ^ (row & 7);
          bf16x8 kf = *reinterpret_cast<const bf16x8*>((const char*)&Ks[buf][0] + row * 128 + s2 * 16);
          s_[j4] = __builtin_amdgcn_mfma_f32_16x16x32_bf16(kf, qf[qs][ks], s_[j4], 0, 0, 0);
        }
      }

      // ---- online softmax in exp2 domain, defer-max (verbatim R4/R8) ----
      float tm = fmaxf(fmaxf(fmaxf(s_[0][0], s_[0][1]), fmaxf(s_[0][2], s_[0][3])),
                       fmaxf(fmaxf(s_[1][0], s_[1][1]), fmaxf(s_[1][2], s_[1][3])));
      tm = fmaxf(tm, fmaxf(fmaxf(fmaxf(s_[2][0], s_[2][1]), fmaxf(s_[2][2], s_[2][3])),
                           fmaxf(fmaxf(s_[3][0], s_[3][1]), fmaxf(s_[3][2], s_[3][3]))));
      tm = fmaxf(tm, __shfl_xor(tm, 16, 64));
      tm = fmaxf(tm, __shfl_xor(tm, 32, 64));
      if (!__all(tm <= m_[qs] + 11.5416f)) {
        const float nm = fmaxf(m_[qs], tm);
        const float fac = EXP2F(m_[qs] - nm);
        m_[qs] = nm;
        l_[qs] *= fac;
#pragma unroll
        for (int r = 0; r < 4; ++r) {
          const float fr = __shfl(fac, (l & 48) | (lq * 4 + r), 64);
          o_[qs][0][r] *= fr; o_[qs][1][r] *= fr;
          o_[qs][2][r] *= fr; o_[qs][3][r] *= fr;
        }
      }
      float rs = 0.f;
#pragma unroll
      for (int j4 = 0; j4 < 4; ++j4) {
        const float p0 = EXP2F(s_[j4][0] - m_[qs]);
        const float p1 = EXP2F(s_[j4][1] - m_[qs]);
        const float p2 = EXP2F(s_[j4][2] - m_[qs]);
        const float p3 = EXP2F(s_[j4][3] - m_[qs]);
        rs += (p0 + p1) + (p2 + p3);
        // pairs (j4*8+lq*2, +1): b64 write, swizzled at 16B granularity
        const int s16 = (j4 * 2 + (lq >> 1)) ^ (lr & 7);
        uint2 pk;
        pk.x = cvt_pk_bf16(p0, p1);
        pk.y = cvt_pk_bf16(p2, p3);
        *reinterpret_cast<uint2*>((char*)&Ps[w][0] + lr * 128 + s16 * 16 + (lq & 1) * 8) = pk;
      }
      rs += __shfl_xor(rs, 16, 64);
      rs += __shfl_xor(rs, 32, 64);
      l_[qs] += rs;

      // ---- O += P V (Ps per-wave: in-wave write->read ordering) ----
#pragma unroll
      for (int ks = 0; ks < 2; ++ks) {
        const int sp = (ks * 4 + lq) ^ (lr & 7);
        bf16x8 pf = *reinterpret_cast<const bf16x8*>((const char*)&Ps[w][0] + lr * 128 + sp * 16);
#pragma unroll
        for (int d = 0; d < 4; ++d) {
          const int rowv = d * 16 + lr;
          const int s2 = (ks * 4 + lq) ^ (rowv & 7);
          bf16x8 vf = *reinterpret_cast<const bf16x8*>((const char*)&VT[buf][0] + rowv * 128 + s2 * 16);
          o_[qs][d] = __builtin_amdgcn_mfma_f32_16x16x32_bf16(pf, vf, o_[qs][d], 0, 0, 0);
        }
      }
    }
    __syncthreads();   // drains vmcnt (next tile staged) + frees buf for overwrite
    buf ^= 1;
  }

  // ---- epilogue: attb[b][n][h*64+d] (bf16), two subtiles ----
#pragma unroll
  for (int qs = 0; qs < 2; ++qs)
#pragma unroll
    for (int r = 0; r < 4; ++r) {
      const float lsum = __shfl(l_[qs], (l & 48) | (lq * 4 + r), 64);
      const float inv = 1.0f / lsum;
      const size_t row = (size_t)bq * NS + q0 + qs * 64 + w * 16 + lq * 4 + r;
#pragma unroll
      for (int d = 0; d < 4; ++d) {
        attb[row * EMB_ + h * HD + d * 16 + lr] = f2bf(o_[qs][d][r] * inv);
      }
    }
}

// ---------------------------------------------------------------------------
extern "C" void kernel_launch(void* const* d_in, const int* in_sizes, int n_in,
                              void* d_out, int out_size, void* d_ws, size_t ws_size,
                              hipStream_t stream) {
  const float* x      = (const float*)d_in[0];
  const float* w_qkv  = (const float*)d_in[1];
  const float* b_qkv  = (const float*)d_in[2];
  const float* w_proj = (const float*)d_in[3];
  const float* b_proj = (const float*)d_in[4];
  float* out = (float*)d_out;

  const size_t per = (size_t)B_ * NH * NS * HD;        // 8,388,608
  unsigned short* qb   = (unsigned short*)d_ws;
  unsigned short* kb   = qb + per;
  unsigned short* vtb  = kb + per;                     // V^T [B][H][HD][NS]
  unsigned short* attb = vtb + per;                    // [B][NS][EMB] bf16
  unsigned short* xb   = attb + (size_t)MR * EMB_;     // x bf16
  unsigned short* wqb  = xb + (size_t)MR * EMB_;
  unsigned short* wpb  = wqb + (size_t)3 * EMB_ * EMB_;

  const int nx = MR * EMB_;
  const int n1 = 3 * EMB_ * EMB_;
  const int n2 = EMB_ * EMB_;
  cvt_kernel<<<2048, 256, 0, stream>>>(x, xb, nx, w_qkv, wqb, n1, w_proj, wpb, n2);

  dim3 g1(MR / 128, 3 * EMB_ / 128);     // 64 x 24
  qkv_mfma_kernel<<<g1, 256, 0, stream>>>(xb, wqb, b_qkv, qb, kb, vtb);

  attn_mfma7_kernel<<<1024, 256, 0, stream>>>(qb, kb, vtb, attb);

  dim3 g3(MR / 128, EMB_ / 128);         // 64 x 8
  proj_mfma_kernel<<<g3, 256, 0, stream>>>(attb, wpb, b_proj, out);
}

// Round 12
// 223.400 us; speedup vs baseline: 1.0367x; 1.0086x over previous
//
#include <hip/hip_runtime.h>
#include <math.h>

#define B_    4
#define NS    2048
#define EMB_  1024
#define NH    16
#define HD    64
#define MR    (B_*NS)        // 8192 rows

typedef __attribute__((ext_vector_type(8))) short bf16x8;
typedef __attribute__((ext_vector_type(4))) float f32x4;

#define AS1 __attribute__((address_space(1)))
#define AS3 __attribute__((address_space(3)))

#if __has_builtin(__builtin_amdgcn_exp2f)
#define EXP2F(x) __builtin_amdgcn_exp2f(x)
#else
#define EXP2F(x) exp2f(x)
#endif

__device__ __forceinline__ unsigned short f2bf(float f) {
  unsigned int x = __float_as_uint(f);
  x += 0x7fffu + ((x >> 16) & 1u);   // round-to-nearest-even
  return (unsigned short)(x >> 16);
}

__device__ __forceinline__ unsigned int cvt_pk_bf16(float lo, float hi) {
  unsigned int r;
  asm("v_cvt_pk_bf16_f32 %0, %1, %2" : "=v"(r) : "v"(lo), "v"(hi));
  return r;
}

// ---------------------------------------------------------------------------
// fp32 -> bf16 conversion for x, w_qkv, w_proj (grid-stride, float4 in)
// ---------------------------------------------------------------------------
__global__ __launch_bounds__(256) void cvt_kernel(
    const float* __restrict__ x,  unsigned short* __restrict__ xb,  int nx,
    const float* __restrict__ w1, unsigned short* __restrict__ w1b, int n1,
    const float* __restrict__ w2, unsigned short* __restrict__ w2b, int n2) {
  const int total = (nx + n1 + n2) >> 2;
  for (int i = blockIdx.x * blockDim.x + threadIdx.x; i < total;
       i += gridDim.x * blockDim.x) {
    const int idx = i << 2;
    const float* src;
    unsigned short* dst;
    if (idx < nx)            { src = x  + idx;            dst = xb  + idx; }
    else if (idx < nx + n1)  { src = w1 + (idx - nx);     dst = w1b + (idx - nx); }
    else                     { src = w2 + (idx - nx - n1); dst = w2b + (idx - nx - n1); }
    float4 v = *reinterpret_cast<const float4*>(src);
    uint2 p;
    p.x = (unsigned)f2bf(v.x) | ((unsigned)f2bf(v.y) << 16);
    p.y = (unsigned)f2bf(v.z) | ((unsigned)f2bf(v.w) << 16);
    *reinterpret_cast<uint2*>(dst) = p;
  }
}

// ---------------------------------------------------------------------------
// Shared MFMA GEMM main loop: C[128x128] tile, BK=64, 4 waves.
// ---------------------------------------------------------------------------
__device__ __forceinline__ void mfma_mainloop(
    const unsigned short* __restrict__ xg,
    const unsigned short* __restrict__ wg,
    unsigned short* Xs, unsigned short* Ws, f32x4 acc[4][4]) {
  const int tid = threadIdx.x;
  const int w = tid >> 6, l = tid & 63;
  const int lr = l & 15, lq = l >> 4;
  const int wm = w >> 1, wn = w & 1;
  const int rr = l >> 3;
  const int sl = (l & 7) ^ rr;

  for (int kt = 0; kt < 16; ++kt) {
    const int k0 = kt * 64;
#pragma unroll
    for (int i = 0; i < 4; ++i) {
      const int r0 = w * 32 + i * 8;
      __builtin_amdgcn_global_load_lds(
          (const AS1 unsigned int*)(const void*)(xg + (size_t)(r0 + rr) * 1024 + k0 + sl * 8),
          (AS3 unsigned int*)(void*)(Xs + r0 * 64), 16, 0, 0);
      __builtin_amdgcn_global_load_lds(
          (const AS1 unsigned int*)(const void*)(wg + (size_t)(r0 + rr) * 1024 + k0 + sl * 8),
          (AS3 unsigned int*)(void*)(Ws + r0 * 64), 16, 0, 0);
    }
    __syncthreads();

#pragma unroll
    for (int ks = 0; ks < 2; ++ks) {
      bf16x8 xf[4], wf[4];
#pragma unroll
      for (int i = 0; i < 4; ++i) {
        const int row = wm * 64 + i * 16 + lr;
        const int s2 = (ks * 4 + lq) ^ (row & 7);
        xf[i] = *reinterpret_cast<const bf16x8*>((const char*)Xs + row * 128 + s2 * 16);
      }
#pragma unroll
      for (int j = 0; j < 4; ++j) {
        const int row = wn * 64 + j * 16 + lr;
        const int s2 = (ks * 4 + lq) ^ (row & 7);
        wf[j] = *reinterpret_cast<const bf16x8*>((const char*)Ws + row * 128 + s2 * 16);
      }
#pragma unroll
      for (int i = 0; i < 4; ++i)
#pragma unroll
        for (int j = 0; j < 4; ++j)
          acc[i][j] = __builtin_amdgcn_mfma_f32_16x16x32_bf16(wf[j], xf[i], acc[i][j], 0, 0, 0);
    }
    __syncthreads();
  }
}

// ---------------------------------------------------------------------------
// GEMM1: qkv = x @ w_qkv^T + b_qkv -> bf16 q/k [B][H][NS][HD] and
// V^T DIRECTLY as vt [B][H][HD][NS] (vtrans fused away).
// q scaled by 0.125*log2(e)  (attention softmax runs in exp2 domain)
// ---------------------------------------------------------------------------
__global__ __launch_bounds__(256) void qkv_mfma_kernel(
    const unsigned short* __restrict__ xb, const unsigned short* __restrict__ wqb,
    const float* __restrict__ bias,
    unsigned short* __restrict__ qb, unsigned short* __restrict__ kb,
    unsigned short* __restrict__ vtb) {
  __shared__ __align__(16) unsigned short Xs[128 * 64];
  __shared__ __align__(16) unsigned short Ws[128 * 64];
  f32x4 acc[4][4];
  const f32x4 fz = {0.f, 0.f, 0.f, 0.f};
#pragma unroll
  for (int i = 0; i < 4; ++i)
#pragma unroll
    for (int j = 0; j < 4; ++j) acc[i][j] = fz;

  const int bm = blockIdx.x * 128, bn = blockIdx.y * 128;
  mfma_mainloop(xb + (size_t)bm * 1024, wqb + (size_t)bn * 1024, Xs, Ws, acc);

  const int tid = threadIdx.x;
  const int w = tid >> 6, l = tid & 63;
  const int lr = l & 15, lq = l >> 4;
  const int wm = w >> 1, wn = w & 1;
#pragma unroll
  for (int i = 0; i < 4; ++i) {
    const int mrow = bm + wm * 64 + i * 16 + lr;
    const int b = mrow >> 11;
    const int nseq = mrow & (NS - 1);
#pragma unroll
    for (int j = 0; j < 4; ++j) {
      const int col0 = bn + wn * 64 + j * 16 + lq * 4;
      const int which = col0 >> 10;
      const int e = col0 & 1023;
      const int hh = e >> 6, d0 = e & 63;
      const float v0 = acc[i][j][0] + bias[col0 + 0];
      const float v1 = acc[i][j][1] + bias[col0 + 1];
      const float v2 = acc[i][j][2] + bias[col0 + 2];
      const float v3 = acc[i][j][3] + bias[col0 + 3];
      if (which < 2) {
        unsigned short* dst = (which == 0) ? qb : kb;
        const float sc = (which == 0) ? 0.18033688f : 1.0f;  // 0.125*log2e
        uint2 pk;
        pk.x = (unsigned)f2bf(v0 * sc) | ((unsigned)f2bf(v1 * sc) << 16);
        pk.y = (unsigned)f2bf(v2 * sc) | ((unsigned)f2bf(v3 * sc) << 16);
        *reinterpret_cast<uint2*>(&dst[(((size_t)b * NH + hh) * NS + nseq) * HD + d0]) = pk;
      } else {
        // V^T: vt[b][h][d][n], d = d0..d0+3 (within one head: d0 <= 60)
        unsigned short* dt =
            vtb + (((size_t)b * NH + hh) * HD + d0) * NS + nseq;
        dt[0 * NS] = f2bf(v0);
        dt[1 * NS] = f2bf(v1);
        dt[2 * NS] = f2bf(v2);
        dt[3 * NS] = f2bf(v3);
      }
    }
  }
}

// ---------------------------------------------------------------------------
// GEMM2: out = att(bf16) @ w_proj^T + b_proj -> fp32
// ---------------------------------------------------------------------------
__global__ __launch_bounds__(256) void proj_mfma_kernel(
    const unsigned short* __restrict__ attb, const unsigned short* __restrict__ wpb,
    const float* __restrict__ bias, float* __restrict__ out) {
  __shared__ __align__(16) unsigned short Xs[128 * 64];
  __shared__ __align__(16) unsigned short Ws[128 * 64];
  f32x4 acc[4][4];
  const f32x4 fz = {0.f, 0.f, 0.f, 0.f};
#pragma unroll
  for (int i = 0; i < 4; ++i)
#pragma unroll
    for (int j = 0; j < 4; ++j) acc[i][j] = fz;

  const int bm = blockIdx.x * 128, bn = blockIdx.y * 128;
  mfma_mainloop(attb + (size_t)bm * 1024, wpb + (size_t)bn * 1024, Xs, Ws, acc);

  const int tid = threadIdx.x;
  const int w = tid >> 6, l = tid & 63;
  const int lr = l & 15, lq = l >> 4;
  const int wm = w >> 1, wn = w & 1;
#pragma unroll
  for (int i = 0; i < 4; ++i) {
    const int mrow = bm + wm * 64 + i * 16 + lr;
#pragma unroll
    for (int j = 0; j < 4; ++j) {
      const int col0 = bn + wn * 64 + j * 16 + lq * 4;
      const float4 b4 = *reinterpret_cast<const float4*>(&bias[col0]);
      float4 v;
      v.x = acc[i][j][0] + b4.x; v.y = acc[i][j][1] + b4.y;
      v.z = acc[i][j][2] + b4.z; v.w = acc[i][j][3] + b4.w;
      *reinterpret_cast<float4*>(&out[(size_t)mrow * EMB_ + col0]) = v;
    }
  }
}

// ---------------------------------------------------------------------------
// Flash attention (round-4/8 PROVEN version, verbatim): swapped QK^T, exp2
// softmax with defer-max, fp32 VALU row-sum, double-buffered global_load_lds
// staging of K and pre-transposed V, dedicated per-wave Ps buffer.
// Block = (b,h,64 q-rows), 4 waves x 16 q-rows, KV tiles of 64.
// ---------------------------------------------------------------------------
__global__ __launch_bounds__(256) void attn_mfma2_kernel(
    const unsigned short* __restrict__ qb, const unsigned short* __restrict__ kb,
    const unsigned short* __restrict__ vt, unsigned short* __restrict__ attb) {
  __shared__ __align__(16) unsigned short Ks[2][64 * 64];   // [kv][d] swizzled
  __shared__ __align__(16) unsigned short VT[2][64 * 64];   // [d][kv] swizzled
  __shared__ __align__(16) unsigned short Ps[4][16 * 64];   // per-wave P [q][kv] swizzled

  // bijective XCD swizzle: 8 XCDs x 256 blocks; each XCD gets 8 whole heads
  const int wg = blockIdx.x;                 // 0..2047
  const int swz = (wg & 7) * 256 + (wg >> 3);
  const int qblk = swz & 31;
  const int head = swz >> 5;                 // 0..63
  const int h = head & 15;
  const int bq = head >> 4;
  const int q0 = qblk * 64;

  const int tid = threadIdx.x;
  const int w = tid >> 6, l = tid & 63;
  const int lr = l & 15, lq = l >> 4;
  const size_t headoff = ((size_t)bq * NH + h) * (size_t)NS * HD;
  const unsigned short* qp = qb + headoff;
  const unsigned short* kp = kb + headoff;
  const unsigned short* vtp = vt + headoff;   // [HD][NS]

  // Q fragments (scale 0.125*log2e folded): B[row=lr][k=lq*8..]
  bf16x8 qf[2];
  {
    const unsigned short* qrow = qp + (size_t)(q0 + w * 16 + lr) * HD + lq * 8;
    qf[0] = *reinterpret_cast<const bf16x8*>(qrow);
    qf[1] = *reinterpret_cast<const bf16x8*>(qrow + 32);
  }

  const f32x4 fz = {0.f, 0.f, 0.f, 0.f};
  float m_ = -1e30f, l_ = 0.f;
  f32x4 o_[4];
#pragma unroll
  for (int d = 0; d < 4; ++d) o_[d] = fz;

  const int srow = l >> 3, sslot = l & 7;

  // ---- prologue: stage tile 0 into buf 0 ----
#pragma unroll
  for (int n = 0; n < 2; ++n) {
    const int r0 = (n * 4 + w) * 8;
    const int row = r0 + srow;
    const int so = (sslot ^ (row & 7)) * 8;
    __builtin_amdgcn_global_load_lds(
        (const AS1 unsigned int*)(const void*)(kp + row * 64 + so),
        (AS3 unsigned int*)(void*)(&Ks[0][0] + r0 * 64), 16, 0, 0);
    __builtin_amdgcn_global_load_lds(
        (const AS1 unsigned int*)(const void*)(vtp + (size_t)row * NS + so),
        (AS3 unsigned int*)(void*)(&VT[0][0] + r0 * 64), 16, 0, 0);
  }
  __syncthreads();

  int buf = 0;
  for (int kt = 0; kt < NS / 64; ++kt) {
    // ---- issue next-tile stage into buf^1 (drained at this iter's barrier) ----
    if (kt < NS / 64 - 1) {
      const unsigned short* knext = kp + (size_t)(kt + 1) * 64 * 64;
      const int vcol = (kt + 1) * 64;
#pragma unroll
      for (int n = 0; n < 2; ++n) {
        const int r0 = (n * 4 + w) * 8;
        const int row = r0 + srow;
        const int so = (sslot ^ (row & 7)) * 8;
        __builtin_amdgcn_global_load_lds(
            (const AS1 unsigned int*)(const void*)(knext + row * 64 + so),
            (AS3 unsigned int*)(void*)(&Ks[buf ^ 1][0] + r0 * 64), 16, 0, 0);
        __builtin_amdgcn_global_load_lds(
            (const AS1 unsigned int*)(const void*)(vtp + (size_t)row * NS + vcol + so),
            (AS3 unsigned int*)(void*)(&VT[buf ^ 1][0] + r0 * 64), 16, 0, 0);
      }
    }

    // ---- S^T = K Q^T : lane holds P[q=lr][kv = j4*16 + lq*4 + r] ----
    f32x4 s_[4];
#pragma unroll
    for (int j4 = 0; j4 < 4; ++j4) s_[j4] = fz;
#pragma unroll
    for (int ks = 0; ks < 2; ++ks) {
#pragma unroll
      for (int j4 = 0; j4 < 4; ++j4) {
        const int row = j4 * 16 + lr;
        const int s2 = (ks * 4 + lq) ^ (row & 7);
        bf16x8 kf = *reinterpret_cast<const bf16x8*>((const char*)&Ks[buf][0] + row * 128 + s2 * 16);
        s_[j4] = __builtin_amdgcn_mfma_f32_16x16x32_bf16(kf, qf[ks], s_[j4], 0, 0, 0);
      }
    }

    // ---- online softmax in exp2 domain, defer-max (THR = 8*log2e) ----
    float tm = fmaxf(fmaxf(fmaxf(s_[0][0], s_[0][1]), fmaxf(s_[0][2], s_[0][3])),
                     fmaxf(fmaxf(s_[1][0], s_[1][1]), fmaxf(s_[1][2], s_[1][3])));
    tm = fmaxf(tm, fmaxf(fmaxf(fmaxf(s_[2][0], s_[2][1]), fmaxf(s_[2][2], s_[2][3])),
                         fmaxf(fmaxf(s_[3][0], s_[3][1]), fmaxf(s_[3][2], s_[3][3]))));
    tm = fmaxf(tm, __shfl_xor(tm, 16, 64));
    tm = fmaxf(tm, __shfl_xor(tm, 32, 64));
    if (!__all(tm <= m_ + 11.5416f)) {
      const float nm = fmaxf(m_, tm);
      const float fac = EXP2F(m_ - nm);
      m_ = nm;
      l_ *= fac;
#pragma unroll
      for (int r = 0; r < 4; ++r) {
        const float fr = __shfl(fac, (l & 48) | (lq * 4 + r), 64);
        o_[0][r] *= fr; o_[1][r] *= fr; o_[2][r] *= fr; o_[3][r] *= fr;
      }
    }
    float rs = 0.f;
#pragma unroll
    for (int j4 = 0; j4 < 4; ++j4) {
      const float p0 = EXP2F(s_[j4][0] - m_);
      const float p1 = EXP2F(s_[j4][1] - m_);
      const float p2 = EXP2F(s_[j4][2] - m_);
      const float p3 = EXP2F(s_[j4][3] - m_);
      rs += (p0 + p1) + (p2 + p3);
      // pairs (j4*8+lq*2, +1): b64 write, swizzled at 16B granularity
      const int s16 = (j4 * 2 + (lq >> 1)) ^ (lr & 7);
      uint2 pk;
      pk.x = cvt_pk_bf16(p0, p1);
      pk.y = cvt_pk_bf16(p2, p3);
      *reinterpret_cast<uint2*>((char*)&Ps[w][0] + lr * 128 + s16 * 16 + (lq & 1) * 8) = pk;
    }
    rs += __shfl_xor(rs, 16, 64);
    rs += __shfl_xor(rs, 32, 64);
    l_ += rs;

    // ---- O += P V ----
#pragma unroll
    for (int ks = 0; ks < 2; ++ks) {
      const int sp = (ks * 4 + lq) ^ (lr & 7);
      bf16x8 pf = *reinterpret_cast<const bf16x8*>((const char*)&Ps[w][0] + lr * 128 + sp * 16);
#pragma unroll
      for (int d = 0; d < 4; ++d) {
        const int rowv = d * 16 + lr;
        const int s2 = (ks * 4 + lq) ^ (rowv & 7);
        bf16x8 vf = *reinterpret_cast<const bf16x8*>((const char*)&VT[buf][0] + rowv * 128 + s2 * 16);
        o_[d] = __builtin_amdgcn_mfma_f32_16x16x32_bf16(pf, vf, o_[d], 0, 0, 0);
      }
    }
    __syncthreads();   // drains vmcnt (next tile staged) + frees buf for overwrite
    buf ^= 1;
  }

  // ---- epilogue: attb[b][n][h*64+d] (bf16) ----
#pragma unroll
  for (int r = 0; r < 4; ++r) {
    const float lsum = __shfl(l_, (l & 48) | (lq * 4 + r), 64);
    const float inv = 1.0f / lsum;
    const size_t row = (size_t)bq * NS + q0 + w * 16 + lq * 4 + r;
#pragma unroll
    for (int d = 0; d < 4; ++d) {
      attb[row * EMB_ + h * HD + d * 16 + lr] = f2bf(o_[d][r] * inv);
    }
  }
}

// ---------------------------------------------------------------------------
extern "C" void kernel_launch(void* const* d_in, const int* in_sizes, int n_in,
                              void* d_out, int out_size, void* d_ws, size_t ws_size,
                              hipStream_t stream) {
  const float* x      = (const float*)d_in[0];
  const float* w_qkv  = (const float*)d_in[1];
  const float* b_qkv  = (const float*)d_in[2];
  const float* w_proj = (const float*)d_in[3];
  const float* b_proj = (const float*)d_in[4];
  float* out = (float*)d_out;

  const size_t per = (size_t)B_ * NH * NS * HD;        // 8,388,608
  unsigned short* qb   = (unsigned short*)d_ws;
  unsigned short* kb   = qb + per;
  unsigned short* vtb  = kb + per;                     // V^T [B][H][HD][NS]
  unsigned short* attb = vtb + per;                    // [B][NS][EMB] bf16
  unsigned short* xb   = attb + (size_t)MR * EMB_;     // x bf16
  unsigned short* wqb  = xb + (size_t)MR * EMB_;
  unsigned short* wpb  = wqb + (size_t)3 * EMB_ * EMB_;

  const int nx = MR * EMB_;
  const int n1 = 3 * EMB_ * EMB_;
  const int n2 = EMB_ * EMB_;
  cvt_kernel<<<2048, 256, 0, stream>>>(x, xb, nx, w_qkv, wqb, n1, w_proj, wpb, n2);

  dim3 g1(MR / 128, 3 * EMB_ / 128);     // 64 x 24
  qkv_mfma_kernel<<<g1, 256, 0, stream>>>(xb, wqb, b_qkv, qb, kb, vtb);

  attn_mfma2_kernel<<<2048, 256, 0, stream>>>(qb, kb, vtb, attb);

  dim3 g3(MR / 128, EMB_ / 128);         // 64 x 8
  proj_mfma_kernel<<<g3, 256, 0, stream>>>(attb, wpb, b_proj, out);
}

// Round 14
// 222.800 us; speedup vs baseline: 1.0395x; 1.0027x over previous
//
#include <hip/hip_runtime.h>
#include <math.h>

#define B_    4
#define NS    2048
#define EMB_  1024
#define NH    16
#define HD    64
#define MR    (B_*NS)        // 8192 rows

typedef __attribute__((ext_vector_type(8))) short bf16x8;
typedef __attribute__((ext_vector_type(4))) float f32x4;

#define AS1 __attribute__((address_space(1)))
#define AS3 __attribute__((address_space(3)))

#if __has_builtin(__builtin_amdgcn_exp2f)
#define EXP2F(x) __builtin_amdgcn_exp2f(x)
#else
#define EXP2F(x) exp2f(x)
#endif

__device__ __forceinline__ unsigned short f2bf(float f) {
  unsigned int x = __float_as_uint(f);
  x += 0x7fffu + ((x >> 16) & 1u);   // round-to-nearest-even
  return (unsigned short)(x >> 16);
}

__device__ __forceinline__ unsigned int cvt_pk_bf16(float lo, float hi) {
  unsigned int r;
  asm("v_cvt_pk_bf16_f32 %0, %1, %2" : "=v"(r) : "v"(lo), "v"(hi));
  return r;
}

// ---------------------------------------------------------------------------
// fp32 -> bf16 conversion for x, w_qkv, w_proj (grid-stride, float4 in)
// ---------------------------------------------------------------------------
__global__ __launch_bounds__(256) void cvt_kernel(
    const float* __restrict__ x,  unsigned short* __restrict__ xb,  int nx,
    const float* __restrict__ w1, unsigned short* __restrict__ w1b, int n1,
    const float* __restrict__ w2, unsigned short* __restrict__ w2b, int n2) {
  const int total = (nx + n1 + n2) >> 2;
  for (int i = blockIdx.x * blockDim.x + threadIdx.x; i < total;
       i += gridDim.x * blockDim.x) {
    const int idx = i << 2;
    const float* src;
    unsigned short* dst;
    if (idx < nx)            { src = x  + idx;            dst = xb  + idx; }
    else if (idx < nx + n1)  { src = w1 + (idx - nx);     dst = w1b + (idx - nx); }
    else                     { src = w2 + (idx - nx - n1); dst = w2b + (idx - nx - n1); }
    float4 v = *reinterpret_cast<const float4*>(src);
    uint2 p;
    p.x = (unsigned)f2bf(v.x) | ((unsigned)f2bf(v.y) << 16);
    p.y = (unsigned)f2bf(v.z) | ((unsigned)f2bf(v.w) << 16);
    *reinterpret_cast<uint2*>(dst) = p;
  }
}

// ---------------------------------------------------------------------------
// Shared MFMA GEMM main loop: C[128x128] tile, BK=64, 4 waves.
// ---------------------------------------------------------------------------
__device__ __forceinline__ void mfma_mainloop(
    const unsigned short* __restrict__ xg,
    const unsigned short* __restrict__ wg,
    unsigned short* Xs, unsigned short* Ws, f32x4 acc[4][4]) {
  const int tid = threadIdx.x;
  const int w = tid >> 6, l = tid & 63;
  const int lr = l & 15, lq = l >> 4;
  const int wm = w >> 1, wn = w & 1;
  const int rr = l >> 3;
  const int sl = (l & 7) ^ rr;

  for (int kt = 0; kt < 16; ++kt) {
    const int k0 = kt * 64;
#pragma unroll
    for (int i = 0; i < 4; ++i) {
      const int r0 = w * 32 + i * 8;
      __builtin_amdgcn_global_load_lds(
          (const AS1 unsigned int*)(const void*)(xg + (size_t)(r0 + rr) * 1024 + k0 + sl * 8),
          (AS3 unsigned int*)(void*)(Xs + r0 * 64), 16, 0, 0);
      __builtin_amdgcn_global_load_lds(
          (const AS1 unsigned int*)(const void*)(wg + (size_t)(r0 + rr) * 1024 + k0 + sl * 8),
          (AS3 unsigned int*)(void*)(Ws + r0 * 64), 16, 0, 0);
    }
    __syncthreads();

#pragma unroll
    for (int ks = 0; ks < 2; ++ks) {
      bf16x8 xf[4], wf[4];
#pragma unroll
      for (int i = 0; i < 4; ++i) {
        const int row = wm * 64 + i * 16 + lr;
        const int s2 = (ks * 4 + lq) ^ (row & 7);
        xf[i] = *reinterpret_cast<const bf16x8*>((const char*)Xs + row * 128 + s2 * 16);
      }
#pragma unroll
      for (int j = 0; j < 4; ++j) {
        const int row = wn * 64 + j * 16 + lr;
        const int s2 = (ks * 4 + lq) ^ (row & 7);
        wf[j] = *reinterpret_cast<const bf16x8*>((const char*)Ws + row * 128 + s2 * 16);
      }
#pragma unroll
      for (int i = 0; i < 4; ++i)
#pragma unroll
        for (int j = 0; j < 4; ++j)
          acc[i][j] = __builtin_amdgcn_mfma_f32_16x16x32_bf16(wf[j], xf[i], acc[i][j], 0, 0, 0);
    }
    __syncthreads();
  }
}

// ---------------------------------------------------------------------------
// GEMM1: qkv = x @ w_qkv^T + b_qkv -> bf16 q/k [B][H][NS][HD] and
// V^T DIRECTLY as vt [B][H][HD][NS] (vtrans fused away).
// q scaled by 0.125*log2(e)  (attention softmax runs in exp2 domain)
// ---------------------------------------------------------------------------
__global__ __launch_bounds__(256) void qkv_mfma_kernel(
    const unsigned short* __restrict__ xb, const unsigned short* __restrict__ wqb,
    const float* __restrict__ bias,
    unsigned short* __restrict__ qb, unsigned short* __restrict__ kb,
    unsigned short* __restrict__ vtb) {
  __shared__ __align__(16) unsigned short Xs[128 * 64];
  __shared__ __align__(16) unsigned short Ws[128 * 64];
  f32x4 acc[4][4];
  const f32x4 fz = {0.f, 0.f, 0.f, 0.f};
#pragma unroll
  for (int i = 0; i < 4; ++i)
#pragma unroll
    for (int j = 0; j < 4; ++j) acc[i][j] = fz;

  const int bm = blockIdx.x * 128, bn = blockIdx.y * 128;
  mfma_mainloop(xb + (size_t)bm * 1024, wqb + (size_t)bn * 1024, Xs, Ws, acc);

  const int tid = threadIdx.x;
  const int w = tid >> 6, l = tid & 63;
  const int lr = l & 15, lq = l >> 4;
  const int wm = w >> 1, wn = w & 1;
#pragma unroll
  for (int i = 0; i < 4; ++i) {
    const int mrow = bm + wm * 64 + i * 16 + lr;
    const int b = mrow >> 11;
    const int nseq = mrow & (NS - 1);
#pragma unroll
    for (int j = 0; j < 4; ++j) {
      const int col0 = bn + wn * 64 + j * 16 + lq * 4;
      const int which = col0 >> 10;
      const int e = col0 & 1023;
      const int hh = e >> 6, d0 = e & 63;
      const float v0 = acc[i][j][0] + bias[col0 + 0];
      const float v1 = acc[i][j][1] + bias[col0 + 1];
      const float v2 = acc[i][j][2] + bias[col0 + 2];
      const float v3 = acc[i][j][3] + bias[col0 + 3];
      if (which < 2) {
        unsigned short* dst = (which == 0) ? qb : kb;
        const float sc = (which == 0) ? 0.18033688f : 1.0f;  // 0.125*log2e
        uint2 pk;
        pk.x = (unsigned)f2bf(v0 * sc) | ((unsigned)f2bf(v1 * sc) << 16);
        pk.y = (unsigned)f2bf(v2 * sc) | ((unsigned)f2bf(v3 * sc) << 16);
        *reinterpret_cast<uint2*>(&dst[(((size_t)b * NH + hh) * NS + nseq) * HD + d0]) = pk;
      } else {
        // V^T: vt[b][h][d][n], d = d0..d0+3 (within one head: d0 <= 60)
        unsigned short* dt =
            vtb + (((size_t)b * NH + hh) * HD + d0) * NS + nseq;
        dt[0 * NS] = f2bf(v0);
        dt[1 * NS] = f2bf(v1);
        dt[2 * NS] = f2bf(v2);
        dt[3 * NS] = f2bf(v3);
      }
    }
  }
}

// ---------------------------------------------------------------------------
// GEMM2: out = att(bf16) @ w_proj^T + b_proj -> fp32
// ---------------------------------------------------------------------------
__global__ __launch_bounds__(256) void proj_mfma_kernel(
    const unsigned short* __restrict__ attb, const unsigned short* __restrict__ wpb,
    const float* __restrict__ bias, float* __restrict__ out) {
  __shared__ __align__(16) unsigned short Xs[128 * 64];
  __shared__ __align__(16) unsigned short Ws[128 * 64];
  f32x4 acc[4][4];
  const f32x4 fz = {0.f, 0.f, 0.f, 0.f};
#pragma unroll
  for (int i = 0; i < 4; ++i)
#pragma unroll
    for (int j = 0; j < 4; ++j) acc[i][j] = fz;

  const int bm = blockIdx.x * 128, bn = blockIdx.y * 128;
  mfma_mainloop(attb + (size_t)bm * 1024, wpb + (size_t)bn * 1024, Xs, Ws, acc);

  const int tid = threadIdx.x;
  const int w = tid >> 6, l = tid & 63;
  const int lr = l & 15, lq = l >> 4;
  const int wm = w >> 1, wn = w & 1;
#pragma unroll
  for (int i = 0; i < 4; ++i) {
    const int mrow = bm + wm * 64 + i * 16 + lr;
#pragma unroll
    for (int j = 0; j < 4; ++j) {
      const int col0 = bn + wn * 64 + j * 16 + lq * 4;
      const float4 b4 = *reinterpret_cast<const float4*>(&bias[col0]);
      float4 v;
      v.x = acc[i][j][0] + b4.x; v.y = acc[i][j][1] + b4.y;
      v.z = acc[i][j][2] + b4.z; v.w = acc[i][j][3] + b4.w;
      *reinterpret_cast<float4*>(&out[(size_t)mrow * EMB_ + col0]) = v;
    }
  }
}

// ---------------------------------------------------------------------------
// Flash attention (round-4/8/12 PROVEN version, verbatim): swapped QK^T, exp2
// softmax with defer-max, fp32 VALU row-sum, double-buffered global_load_lds
// staging of K and pre-transposed V, dedicated per-wave Ps buffer.
// Block = (b,h,64 q-rows), 4 waves x 16 q-rows, KV tiles of 64.
// ---------------------------------------------------------------------------
__global__ __launch_bounds__(256) void attn_mfma2_kernel(
    const unsigned short* __restrict__ qb, const unsigned short* __restrict__ kb,
    const unsigned short* __restrict__ vt, unsigned short* __restrict__ attb) {
  __shared__ __align__(16) unsigned short Ks[2][64 * 64];   // [kv][d] swizzled
  __shared__ __align__(16) unsigned short VT[2][64 * 64];   // [d][kv] swizzled
  __shared__ __align__(16) unsigned short Ps[4][16 * 64];   // per-wave P [q][kv] swizzled

  // bijective XCD swizzle: 8 XCDs x 256 blocks; each XCD gets 8 whole heads
  const int wg = blockIdx.x;                 // 0..2047
  const int swz = (wg & 7) * 256 + (wg >> 3);
  const int qblk = swz & 31;
  const int head = swz >> 5;                 // 0..63
  const int h = head & 15;
  const int bq = head >> 4;
  const int q0 = qblk * 64;

  const int tid = threadIdx.x;
  const int w = tid >> 6, l = tid & 63;
  const int lr = l & 15, lq = l >> 4;
  const size_t headoff = ((size_t)bq * NH + h) * (size_t)NS * HD;
  const unsigned short* qp = qb + headoff;
  const unsigned short* kp = kb + headoff;
  const unsigned short* vtp = vt + headoff;   // [HD][NS]

  // Q fragments (scale 0.125*log2e folded): B[row=lr][k=lq*8..]
  bf16x8 qf[2];
  {
    const unsigned short* qrow = qp + (size_t)(q0 + w * 16 + lr) * HD + lq * 8;
    qf[0] = *reinterpret_cast<const bf16x8*>(qrow);
    qf[1] = *reinterpret_cast<const bf16x8*>(qrow + 32);
  }

  const f32x4 fz = {0.f, 0.f, 0.f, 0.f};
  float m_ = -1e30f, l_ = 0.f;
  f32x4 o_[4];
#pragma unroll
  for (int d = 0; d < 4; ++d) o_[d] = fz;

  const int srow = l >> 3, sslot = l & 7;

  // ---- prologue: stage tile 0 into buf 0 ----
#pragma unroll
  for (int n = 0; n < 2; ++n) {
    const int r0 = (n * 4 + w) * 8;
    const int row = r0 + srow;
    const int so = (sslot ^ (row & 7)) * 8;
    __builtin_amdgcn_global_load_lds(
        (const AS1 unsigned int*)(const void*)(kp + row * 64 + so),
        (AS3 unsigned int*)(void*)(&Ks[0][0] + r0 * 64), 16, 0, 0);
    __builtin_amdgcn_global_load_lds(
        (const AS1 unsigned int*)(const void*)(vtp + (size_t)row * NS + so),
        (AS3 unsigned int*)(void*)(&VT[0][0] + r0 * 64), 16, 0, 0);
  }
  __syncthreads();

  int buf = 0;
  for (int kt = 0; kt < NS / 64; ++kt) {
    // ---- issue next-tile stage into buf^1 (drained at this iter's barrier) ----
    if (kt < NS / 64 - 1) {
      const unsigned short* knext = kp + (size_t)(kt + 1) * 64 * 64;
      const int vcol = (kt + 1) * 64;
#pragma unroll
      for (int n = 0; n < 2; ++n) {
        const int r0 = (n * 4 + w) * 8;
        const int row = r0 + srow;
        const int so = (sslot ^ (row & 7)) * 8;
        __builtin_amdgcn_global_load_lds(
            (const AS1 unsigned int*)(const void*)(knext + row * 64 + so),
            (AS3 unsigned int*)(void*)(&Ks[buf ^ 1][0] + r0 * 64), 16, 0, 0);
        __builtin_amdgcn_global_load_lds(
            (const AS1 unsigned int*)(const void*)(vtp + (size_t)row * NS + vcol + so),
            (AS3 unsigned int*)(void*)(&VT[buf ^ 1][0] + r0 * 64), 16, 0, 0);
      }
    }

    // ---- S^T = K Q^T : lane holds P[q=lr][kv = j4*16 + lq*4 + r] ----
    f32x4 s_[4];
#pragma unroll
    for (int j4 = 0; j4 < 4; ++j4) s_[j4] = fz;
#pragma unroll
    for (int ks = 0; ks < 2; ++ks) {
#pragma unroll
      for (int j4 = 0; j4 < 4; ++j4) {
        const int row = j4 * 16 + lr;
        const int s2 = (ks * 4 + lq) ^ (row & 7);
        bf16x8 kf = *reinterpret_cast<const bf16x8*>((const char*)&Ks[buf][0] + row * 128 + s2 * 16);
        s_[j4] = __builtin_amdgcn_mfma_f32_16x16x32_bf16(kf, qf[ks], s_[j4], 0, 0, 0);
      }
    }

    // ---- online softmax in exp2 domain, defer-max (THR = 8*log2e) ----
    float tm = fmaxf(fmaxf(fmaxf(s_[0][0], s_[0][1]), fmaxf(s_[0][2], s_[0][3])),
                     fmaxf(fmaxf(s_[1][0], s_[1][1]), fmaxf(s_[1][2], s_[1][3])));
    tm = fmaxf(tm, fmaxf(fmaxf(fmaxf(s_[2][0], s_[2][1]), fmaxf(s_[2][2], s_[2][3])),
                         fmaxf(fmaxf(s_[3][0], s_[3][1]), fmaxf(s_[3][2], s_[3][3]))));
    tm = fmaxf(tm, __shfl_xor(tm, 16, 64));
    tm = fmaxf(tm, __shfl_xor(tm, 32, 64));
    if (!__all(tm <= m_ + 11.5416f)) {
      const float nm = fmaxf(m_, tm);
      const float fac = EXP2F(m_ - nm);
      m_ = nm;
      l_ *= fac;
#pragma unroll
      for (int r = 0; r < 4; ++r) {
        const float fr = __shfl(fac, (l & 48) | (lq * 4 + r), 64);
        o_[0][r] *= fr; o_[1][r] *= fr; o_[2][r] *= fr; o_[3][r] *= fr;
      }
    }
    float rs = 0.f;
#pragma unroll
    for (int j4 = 0; j4 < 4; ++j4) {
      const float p0 = EXP2F(s_[j4][0] - m_);
      const float p1 = EXP2F(s_[j4][1] - m_);
      const float p2 = EXP2F(s_[j4][2] - m_);
      const float p3 = EXP2F(s_[j4][3] - m_);
      rs += (p0 + p1) + (p2 + p3);
      // pairs (j4*8+lq*2, +1): b64 write, swizzled at 16B granularity
      const int s16 = (j4 * 2 + (lq >> 1)) ^ (lr & 7);
      uint2 pk;
      pk.x = cvt_pk_bf16(p0, p1);
      pk.y = cvt_pk_bf16(p2, p3);
      *reinterpret_cast<uint2*>((char*)&Ps[w][0] + lr * 128 + s16 * 16 + (lq & 1) * 8) = pk;
    }
    rs += __shfl_xor(rs, 16, 64);
    rs += __shfl_xor(rs, 32, 64);
    l_ += rs;

    // ---- O += P V ----
#pragma unroll
    for (int ks = 0; ks < 2; ++ks) {
      const int sp = (ks * 4 + lq) ^ (lr & 7);
      bf16x8 pf = *reinterpret_cast<const bf16x8*>((const char*)&Ps[w][0] + lr * 128 + sp * 16);
#pragma unroll
      for (int d = 0; d < 4; ++d) {
        const int rowv = d * 16 + lr;
        const int s2 = (ks * 4 + lq) ^ (rowv & 7);
        bf16x8 vf = *reinterpret_cast<const bf16x8*>((const char*)&VT[buf][0] + rowv * 128 + s2 * 16);
        o_[d] = __builtin_amdgcn_mfma_f32_16x16x32_bf16(pf, vf, o_[d], 0, 0, 0);
      }
    }
    __syncthreads();   // drains vmcnt (next tile staged) + frees buf for overwrite
    buf ^= 1;
  }

  // ---- epilogue: attb[b][n][h*64+d] (bf16) ----
#pragma unroll
  for (int r = 0; r < 4; ++r) {
    const float lsum = __shfl(l_, (l & 48) | (lq * 4 + r), 64);
    const float inv = 1.0f / lsum;
    const size_t row = (size_t)bq * NS + q0 + w * 16 + lq * 4 + r;
#pragma unroll
    for (int d = 0; d < 4; ++d) {
      attb[row * EMB_ + h * HD + d * 16 + lr] = f2bf(o_[d][r] * inv);
    }
  }
}

// ---------------------------------------------------------------------------
extern "C" void kernel_launch(void* const* d_in, const int* in_sizes, int n_in,
                              void* d_out, int out_size, void* d_ws, size_t ws_size,
                              hipStream_t stream) {
  const float* x      = (const float*)d_in[0];
  const float* w_qkv  = (const float*)d_in[1];
  const float* b_qkv  = (const float*)d_in[2];
  const float* w_proj = (const float*)d_in[3];
  const float* b_proj = (const float*)d_in[4];
  float* out = (float*)d_out;

  const size_t per = (size_t)B_ * NH * NS * HD;        // 8,388,608
  unsigned short* qb   = (unsigned short*)d_ws;
  unsigned short* kb   = qb + per;
  unsigned short* vtb  = kb + per;                     // V^T [B][H][HD][NS]
  unsigned short* attb = vtb + per;                    // [B][NS][EMB] bf16
  unsigned short* xb   = attb + (size_t)MR * EMB_;     // x bf16
  unsigned short* wqb  = xb + (size_t)MR * EMB_;
  unsigned short* wpb  = wqb + (size_t)3 * EMB_ * EMB_;

  const int nx = MR * EMB_;
  const int n1 = 3 * EMB_ * EMB_;
  const int n2 = EMB_ * EMB_;
  cvt_kernel<<<2048, 256, 0, stream>>>(x, xb, nx, w_qkv, wqb, n1, w_proj, wpb, n2);

  dim3 g1(MR / 128, 3 * EMB_ / 128);     // 64 x 24
  qkv_mfma_kernel<<<g1, 256, 0, stream>>>(xb, wqb, b_qkv, qb, kb, vtb);

  attn_mfma2_kernel<<<2048, 256, 0, stream>>>(qb, kb, vtb, attb);

  dim3 g3(MR / 128, EMB_ / 128);         // 64 x 8
  proj_mfma_kernel<<<g3, 256, 0, stream>>>(attb, wpb, b_proj, out);
}